// Round 2
// baseline (558.231 us; speedup 1.0000x reference)
//
#include <hip/hip_runtime.h>
#include <hip/hip_bf16.h>
#include <math.h>

// Problem constants
#define B_TOK 4096
#define NE 16
#define DI 1024
#define DH 2048
#define DOUT 1024
#define NSLOT (B_TOK * 2)   // 8192 (token, expert) assignments, exactly

typedef unsigned short u16;
typedef short bfrag __attribute__((ext_vector_type(8)));   // 8 bf16 input frag (4 VGPRs)
typedef float f32x4 __attribute__((ext_vector_type(4)));   // MFMA accumulator
typedef u16 u16x8 __attribute__((ext_vector_type(8)));

// ---------- helpers ----------
__device__ __forceinline__ u16 f2bf(float f) {   // fp32 -> bf16 round-to-nearest-even
    union { float f; unsigned u; } v; v.f = f;
    return (u16)((v.u + 0x7fffu + ((v.u >> 16) & 1u)) >> 16);
}

// async 16B/lane global->LDS. LDS dest must be wave-uniform base (+lane*16 by HW).
__device__ __forceinline__ void async16(const void* g, void* lds) {
    __builtin_amdgcn_global_load_lds(
        (const __attribute__((address_space(1))) void*)g,
        (__attribute__((address_space(3))) void*)lds,
        16, 0, 0);
}

// ---------- kernel 0: zero output ----------
__global__ void zero_init(float* __restrict__ out, int n4) {
    int i = blockIdx.x * blockDim.x + threadIdx.x;
    if (i < n4) ((float4*)out)[i] = make_float4(0.f, 0.f, 0.f, 0.f);
}

// ---------- kernel 1: fp32 -> bf16 convert, 8 elems/thread ----------
__global__ void convert_bf16(const float* __restrict__ src, u16* __restrict__ dst, int n8) {
    int i = blockIdx.x * blockDim.x + threadIdx.x;
    if (i >= n8) return;
    const float4* s4 = (const float4*)src;
    float4 a = s4[2 * i], b = s4[2 * i + 1];
    u16x8 r;
    r[0] = f2bf(a.x); r[1] = f2bf(a.y); r[2] = f2bf(a.z); r[3] = f2bf(a.w);
    r[4] = f2bf(b.x); r[5] = f2bf(b.y); r[6] = f2bf(b.z); r[7] = f2bf(b.w);
    ((u16x8*)dst)[i] = r;
}

// ---------- kernel 2: gating (fp64 dots for exact top-k ordering; NO global atomics) ----------
__global__ __launch_bounds__(256) void gate_topk(
    const float* __restrict__ x, const float* __restrict__ gw,
    int* __restrict__ token_e, float* __restrict__ token_w)
{
    int wave = threadIdx.x >> 6, lane = threadIdx.x & 63;
    int t = blockIdx.x * 4 + wave;            // grid 1024 * 4 waves = 4096 tokens
    const float4* x4 = (const float4*)(x + (size_t)t * DI);
    const float4* g4 = (const float4*)gw;
    double acc[NE];
#pragma unroll
    for (int e = 0; e < NE; ++e) acc[e] = 0.0;
#pragma unroll
    for (int i = 0; i < 4; ++i) {
        float4 xv = x4[lane + i * 64];
#pragma unroll
        for (int e = 0; e < NE; ++e) {
            float4 gv = g4[e * 256 + lane + i * 64];
            acc[e] += (double)xv.x * gv.x + (double)xv.y * gv.y
                    + (double)xv.z * gv.z + (double)xv.w * gv.w;
        }
    }
#pragma unroll
    for (int e = 0; e < NE; ++e) {
        double v = acc[e];
        for (int off = 32; off; off >>= 1) v += __shfl_xor(v, off, 64);
        acc[e] = v;
    }
    if (lane == 0) {
        int e0 = 0; double v0 = acc[0];
#pragma unroll
        for (int e = 1; e < NE; ++e) if (acc[e] > v0) { v0 = acc[e]; e0 = e; }
        int e1 = -1; double v1 = -1e300;
#pragma unroll
        for (int e = 0; e < NE; ++e) if (e != e0 && acc[e] > v1) { v1 = acc[e]; e1 = e; }
        float d = expf((float)(v1 - v0));        // v1 <= v0, d in (0,1]
        float w0 = 1.f / (1.f + d);
        float w1 = d * w0;
        token_e[2 * t] = e0; token_e[2 * t + 1] = e1;
        token_w[2 * t] = w0; token_w[2 * t + 1] = w1;
    }
}

// ---------- kernel 3: routing — histogram + scan + slot fill, one block, LDS atomics ----------
__global__ __launch_bounds__(1024) void route(
    const int* __restrict__ token_e, const float* __restrict__ token_w,
    int* __restrict__ counts, int* __restrict__ offsets,
    int* __restrict__ slot_token, float* __restrict__ slot_wgt)
{
    __shared__ int lcnt[NE];
    __shared__ int lcur[NE];
    int tid = threadIdx.x;
    if (tid < NE) lcnt[tid] = 0;
    __syncthreads();
    for (int i = tid; i < NSLOT; i += 1024) atomicAdd(&lcnt[token_e[i]], 1);
    __syncthreads();
    if (tid == 0) {
        int s = 0;
        for (int e = 0; e < NE; ++e) {
            int c = lcnt[e];
            counts[e] = c; offsets[e] = s; lcur[e] = s; s += c;
        }
    }
    __syncthreads();
    for (int i = tid; i < NSLOT; i += 1024) {
        int e = token_e[i];
        int pos = atomicAdd(&lcur[e], 1);
        slot_token[pos] = i >> 1;
        slot_wgt[pos] = token_w[i];
    }
}

// ---------- grouped GEMM v3: 256-row tiles, BK=64, 8 waves, dbuf, XOR-swizzled LDS ----------
// PHASE1: BM=256 BN=256 (wave tile 128x64, MF=8 NF=4), LDS 2*64KB=128KB, nk=16
// PHASE2: BM=256 BN=128 (wave tile  64x64, MF=4 NF=4), LDS 2*48KB= 96KB, nk=32
// Loop: [stage(kt+1 -> buf^1); ds_read+MFMA(buf); __syncthreads (drain)] — the compute
// phase (~600-1000cy at this tile size) now exceeds the L3/HBM miss latency, so the
// end-of-iter vmcnt(0) drain waits on nearly-complete loads (round-1's 128^2 phase was
// only ~300cy and left 400-600cy exposed -> MfmaUtil 14%).
// LDS swizzle (G4 / rule #21): rows are 128B (8 x 16B chunks); physical chunk = c ^ (r&7).
// global_load_lds writes linearly, so the *global source* is pre-swizzled per lane
// (one async16 = 8 rows x 8 chunks = 64 lanes) and ds_reads apply the same XOR.
template <int PHASE>
__global__ __launch_bounds__(512, 2) void moe_gemm(
    const u16* __restrict__ Abuf,   // PHASE1: xb [4096][1024]; PHASE2: hb [8192][2048]
    const u16* __restrict__ Bbuf,   // bf16 weights: [NE][NDIM][KDIM] (K contiguous)
    const float* __restrict__ bias, // [NE][NDIM] fp32
    const int* __restrict__ counts, const int* __restrict__ offsets,
    const int* __restrict__ slot_token, const float* __restrict__ slot_wgt,
    u16* __restrict__ hb, float* __restrict__ out)
{
    constexpr int KDIM = (PHASE == 1) ? DI : DH;
    constexpr int NDIM = (PHASE == 1) ? DH : DOUT;
    constexpr int BM = 256;
    constexpr int BN = (PHASE == 1) ? 256 : 128;
    constexpr int BK = 64;                        // row = 128B = 8 x 16B chunks
    constexpr int WTM = (PHASE == 1) ? 128 : 64;  // wave tile M
    constexpr int WTN = 64;                       // wave tile N
    constexpr int MF = WTM / 16, NF = WTN / 16;   // frags per wave
    constexpr int GA = BM / 8;                    // A staging groups (8 rows x 128B = 1KB)
    constexpr int GB = BN / 8;
    constexpr int GPW = (GA + GB) / 8;            // groups per wave (8 / 6)
    constexpr int BUFU = (BM + BN) * BK;          // u16 per LDS buffer
    constexpr int NT = NDIM / BN;                 // 8 for both phases
    constexpr int MT = B_TOK / BM;                // 16
    constexpr int PER_XCD = (NE * NT * MT) / 8;   // 2048/8 = 256

    // XCD-chunked bijective swizzle; e-major, then n-tile, then m-tile (mt-consecutive
    // blocks share the B sub-panel in their XCD's L2; each XCD owns exactly 2 experts)
    const int id = blockIdx.x;
    const int wg = (id & 7) * PER_XCD + (id >> 3);
    const int e  = wg / (NT * MT);
    const int rem = wg % (NT * MT);
    const int nt = rem / MT;
    const int mt = rem % MT;

    const int cnt = counts[e];
    const int m0 = mt * BM;
    if (m0 >= cnt) return;                    // block-uniform early exit (before any barrier)
    const int n0 = nt * BN;
    const int sbase = offsets[e];

    __shared__ u16 lds[2][BUFU];

    const int tid = threadIdx.x;
    const int wv = tid >> 6, lane = tid & 63;
    const int quad = lane >> 4, mr = lane & 15;
    const int wr = (PHASE == 1) ? (wv >> 2) : (wv >> 1);   // wave M index
    const int wc = (PHASE == 1) ? (wv & 3)  : (wv & 1);    // wave N index

    // ---- staging pointers: per-lane global source, pre-swizzled (rule #21) ----
    // lane covers (r = lane>>3, s = lane&7) of an 8x128B group; fetches logical chunk s^r
    const int sr_ = lane >> 3, sc_ = lane & 7;
    const int sw = (sc_ ^ sr_) * 8;                        // u16 offset within row
    const u16* gptr[GPW];
#pragma unroll
    for (int j = 0; j < GPW; ++j) {
        const int G = wv * GPW + j;                        // wave-uniform
        if (G < GA) {                                      // A group: tile rows 8G..8G+7
            int row = G * 8 + sr_;
            if (PHASE == 1) {
                int rr = m0 + row; if (rr > cnt - 1) rr = cnt - 1;
                gptr[j] = Abuf + (size_t)slot_token[sbase + rr] * KDIM + sw;
            } else {
                int sr2 = sbase + m0 + row; if (sr2 > NSLOT - 1) sr2 = NSLOT - 1;
                gptr[j] = Abuf + (size_t)sr2 * KDIM + sw;
            }
        } else {                                           // B group
            int row = (G - GA) * 8 + sr_;
            gptr[j] = Bbuf + (size_t)e * NDIM * KDIM + (size_t)(n0 + row) * KDIM + sw;
        }
    }

    f32x4 acc[MF][NF];
#pragma unroll
    for (int i = 0; i < MF; ++i)
#pragma unroll
        for (int j = 0; j < NF; ++j) acc[i][j] = (f32x4){0.f, 0.f, 0.f, 0.f};

    const int nk = KDIM / BK;

    // prologue: stage tile 0 into buffer 0 (GPW async16 per wave; LDS dest linear)
#pragma unroll
    for (int j = 0; j < GPW; ++j)
        async16(gptr[j], &lds[0][(wv * GPW + j) * 512]);
    __syncthreads();                           // drain tile 0

    for (int kt = 0; kt < nk; ++kt) {
        const int bb = kt & 1;
        if (kt + 1 < nk) {                     // prefetch next tile FIRST
#pragma unroll
            for (int j = 0; j < GPW; ++j)
                async16(gptr[j] + (kt + 1) * BK, &lds[bb ^ 1][(wv * GPW + j) * 512]);
        }
        const u16* al = &lds[bb][0];
        const u16* bl = al + BM * BK;
#pragma unroll
        for (int ks = 0; ks < 2; ++ks) {       // two 32-wide k-slices per BK=64
            const int cp = ((ks * 4 + quad) ^ (mr & 7)) * 8;   // swizzled chunk (u16 units)
            bfrag bf[NF];
#pragma unroll
            for (int nf = 0; nf < NF; ++nf)
                bf[nf] = *(const bfrag*)(bl + (wc * WTN + nf * 16 + mr) * BK + cp);
#pragma unroll
            for (int mf = 0; mf < MF; ++mf) {
                bfrag af = *(const bfrag*)(al + (wr * WTM + mf * 16 + mr) * BK + cp);
#pragma unroll
                for (int nf = 0; nf < NF; ++nf)
                    acc[mf][nf] = __builtin_amdgcn_mfma_f32_16x16x32_bf16(af, bf[nf], acc[mf][nf], 0, 0, 0);
            }
        }
        __syncthreads();   // drains vmcnt(0): tile kt+1 landed; buf[bb] free for reuse
    }

    // epilogue. C/D layout: n = lane&15 (=mr), m = quad*4 + reg  [m89-verified]
    const float* bias_e = bias + e * NDIM;
    if constexpr (PHASE == 1) {
#pragma unroll
        for (int mf = 0; mf < MF; ++mf) {
            int mbase = wr * WTM + mf * 16 + quad * 4;
#pragma unroll
            for (int nf = 0; nf < NF; ++nf) {
                int n = n0 + wc * WTN + nf * 16 + mr;
                float bv = bias_e[n];
#pragma unroll
                for (int r = 0; r < 4; ++r) {
                    int m = m0 + mbase + r;
                    if (m < cnt) {
                        float v = acc[mf][nf][r] + bv;
                        v = v > 0.f ? v : 0.f;
                        hb[(size_t)(sbase + m) * DH + n] = f2bf(v);
                    }
                }
            }
        }
    } else {
#pragma unroll
        for (int mf = 0; mf < MF; ++mf) {
            int mbase = wr * WTM + mf * 16 + quad * 4;
#pragma unroll
            for (int r = 0; r < 4; ++r) {
                int m = m0 + mbase + r;
                if (m < cnt) {
                    int slot = sbase + m;
                    int tok = slot_token[slot];
                    float wgt = slot_wgt[slot];
                    float* orow = out + (size_t)tok * DOUT + n0 + wc * WTN;
#pragma unroll
                    for (int nf = 0; nf < NF; ++nf) {
                        int nl = nf * 16 + mr;
                        float v = wgt * (acc[mf][nf][r] + bias_e[n0 + wc * WTN + nl]);
                        atomicAdd(orow + nl, v);
                    }
                }
            }
        }
    }
}

// ---------- launch ----------
extern "C" void kernel_launch(void* const* d_in, const int* in_sizes, int n_in,
                              void* d_out, int out_size, void* d_ws, size_t ws_size,
                              hipStream_t stream) {
    const float* x  = (const float*)d_in[0];   // [4096][1024]
    const float* gw = (const float*)d_in[1];   // [16][1024]
    const float* w1 = (const float*)d_in[2];   // [16][2048][1024]
    const float* b1 = (const float*)d_in[3];   // [16][2048]
    const float* w2 = (const float*)d_in[4];   // [16][1024][2048]
    const float* b2 = (const float*)d_in[5];   // [16][1024]
    float* out = (float*)d_out;                // [4096][1024] fp32

    // workspace layout (~104.1 MiB)
    char* ws = (char*)d_ws;
    u16* xb = (u16*)ws;                                   //  8,388,608 B
    u16* wb = (u16*)(ws + 8388608);                       // 67,108,864 B (w1 then reused for w2)
    u16* hb = (u16*)(ws + 8388608 + 67108864);            // 33,554,432 B
    char* rb = ws + 109051904;
    int*   counts     = (int*)(rb);
    int*   offsets    = (int*)(rb + 64);
    int*   token_e    = (int*)(rb + 192);
    float* token_w    = (float*)(rb + 192 + 32768);
    int*   slot_token = (int*)(rb + 192 + 65536);
    float* slot_wgt   = (float*)(rb + 192 + 98304);

    zero_init<<<4096, 256, 0, stream>>>(out, (B_TOK * DOUT) / 4);
    convert_bf16<<<2048, 256, 0, stream>>>(x, xb, (B_TOK * DI) / 8);
    convert_bf16<<<16384, 256, 0, stream>>>(w1, wb, (NE * DH * DI) / 8);
    gate_topk<<<1024, 256, 0, stream>>>(x, gw, token_e, token_w);
    route<<<1, 1024, 0, stream>>>(token_e, token_w, counts, offsets, slot_token, slot_wgt);
    moe_gemm<1><<<NE * (DH / 256) * (B_TOK / 256) * 16 / 16, 512, 0, stream>>>(
        xb, wb, b1, counts, offsets, slot_token, slot_wgt, hb, out);
    convert_bf16<<<16384, 256, 0, stream>>>(w2, wb, (NE * DOUT * DH) / 8);
    moe_gemm<2><<<NE * (DOUT / 128) * (B_TOK / 256), 512, 0, stream>>>(
        hb, wb, b2, counts, offsets, slot_token, slot_wgt, hb, out);
}

// Round 3
// 493.976 us; speedup vs baseline: 1.1301x; 1.1301x over previous
//
#include <hip/hip_runtime.h>
#include <hip/hip_bf16.h>
#include <math.h>

// Problem constants
#define B_TOK 4096
#define NE 16
#define DI 1024
#define DH 2048
#define DOUT 1024
#define NSLOT (B_TOK * 2)   // 8192 (token, expert) assignments, exactly

typedef unsigned short u16;
typedef short bfrag __attribute__((ext_vector_type(8)));   // 8 bf16 input frag (4 VGPRs)
typedef float f32x4 __attribute__((ext_vector_type(4)));   // MFMA accumulator
typedef u16 u16x4 __attribute__((ext_vector_type(4)));
typedef u16 u16x8 __attribute__((ext_vector_type(8)));

// ---------- helpers ----------
__device__ __forceinline__ u16 f2bf(float f) {   // fp32 -> bf16 round-to-nearest-even
    union { float f; unsigned u; } v; v.f = f;
    return (u16)((v.u + 0x7fffu + ((v.u >> 16) & 1u)) >> 16);
}

// async 16B/lane global->LDS. LDS dest must be wave-uniform base (+lane*16 by HW).
__device__ __forceinline__ void async16(const void* g, void* lds) {
    __builtin_amdgcn_global_load_lds(
        (const __attribute__((address_space(1))) void*)g,
        (__attribute__((address_space(3))) void*)lds,
        16, 0, 0);
}

// ---------- kernel 0: zero output ----------
__global__ void zero_init(float* __restrict__ out, int n4) {
    int i = blockIdx.x * blockDim.x + threadIdx.x;
    if (i < n4) ((float4*)out)[i] = make_float4(0.f, 0.f, 0.f, 0.f);
}

// ---------- kernel 1: fp32 -> bf16 convert, 8 elems/thread (weights) ----------
__global__ void convert_bf16(const float* __restrict__ src, u16* __restrict__ dst, int n8) {
    int i = blockIdx.x * blockDim.x + threadIdx.x;
    if (i >= n8) return;
    const float4* s4 = (const float4*)src;
    float4 a = s4[2 * i], b = s4[2 * i + 1];
    u16x8 r;
    r[0] = f2bf(a.x); r[1] = f2bf(a.y); r[2] = f2bf(a.z); r[3] = f2bf(a.w);
    r[4] = f2bf(b.x); r[5] = f2bf(b.y); r[6] = f2bf(b.z); r[7] = f2bf(b.w);
    ((u16x8*)dst)[i] = r;
}

// ---------- kernel 2: gating (fp64 dots for exact top-k ordering) + fused x->bf16 ----------
__global__ __launch_bounds__(256) void gate_topk(
    const float* __restrict__ x, const float* __restrict__ gw,
    int* __restrict__ token_e, float* __restrict__ token_w,
    u16* __restrict__ xb)
{
    int wave = threadIdx.x >> 6, lane = threadIdx.x & 63;
    int t = blockIdx.x * 4 + wave;            // grid 1024 * 4 waves = 4096 tokens
    const float4* x4 = (const float4*)(x + (size_t)t * DI);
    const float4* g4 = (const float4*)gw;
    u16x4* xb4 = (u16x4*)(xb + (size_t)t * DI);
    double acc[NE];
#pragma unroll
    for (int e = 0; e < NE; ++e) acc[e] = 0.0;
#pragma unroll
    for (int i = 0; i < 4; ++i) {
        float4 xv = x4[lane + i * 64];
        u16x4 xc; xc[0] = f2bf(xv.x); xc[1] = f2bf(xv.y); xc[2] = f2bf(xv.z); xc[3] = f2bf(xv.w);
        xb4[lane + i * 64] = xc;              // fused x convert (coalesced 8B/lane)
#pragma unroll
        for (int e = 0; e < NE; ++e) {
            float4 gv = g4[e * 256 + lane + i * 64];
            acc[e] += (double)xv.x * gv.x + (double)xv.y * gv.y
                    + (double)xv.z * gv.z + (double)xv.w * gv.w;
        }
    }
#pragma unroll
    for (int e = 0; e < NE; ++e) {
        double v = acc[e];
        for (int off = 32; off; off >>= 1) v += __shfl_xor(v, off, 64);
        acc[e] = v;
    }
    if (lane == 0) {
        int e0 = 0; double v0 = acc[0];
#pragma unroll
        for (int e = 1; e < NE; ++e) if (acc[e] > v0) { v0 = acc[e]; e0 = e; }
        int e1 = -1; double v1 = -1e300;
#pragma unroll
        for (int e = 0; e < NE; ++e) if (e != e0 && acc[e] > v1) { v1 = acc[e]; e1 = e; }
        float d = expf((float)(v1 - v0));        // v1 <= v0, d in (0,1]
        float w0 = 1.f / (1.f + d);
        float w1 = d * w0;
        token_e[2 * t] = e0; token_e[2 * t + 1] = e1;
        token_w[2 * t] = w0; token_w[2 * t + 1] = w1;
    }
}

// ---------- kernel 3: routing — histogram + scan + slot fill, one block, LDS atomics ----------
__global__ __launch_bounds__(1024) void route(
    const int* __restrict__ token_e, const float* __restrict__ token_w,
    int* __restrict__ counts, int* __restrict__ offsets,
    int* __restrict__ slot_token, float* __restrict__ slot_wgt)
{
    __shared__ int lcnt[NE];
    __shared__ int lcur[NE];
    int tid = threadIdx.x;
    if (tid < NE) lcnt[tid] = 0;
    __syncthreads();
    for (int i = tid; i < NSLOT; i += 1024) atomicAdd(&lcnt[token_e[i]], 1);
    __syncthreads();
    if (tid == 0) {
        int s = 0;
        for (int e = 0; e < NE; ++e) {
            int c = lcnt[e];
            counts[e] = c; offsets[e] = s; lcur[e] = s; s += c;
        }
    }
    __syncthreads();
    for (int i = tid; i < NSLOT; i += 1024) {
        int e = token_e[i];
        int pos = atomicAdd(&lcur[e], 1);
        slot_token[pos] = i >> 1;
        slot_wgt[pos] = token_w[i];
    }
}

// ---------- grouped GEMM v4: 128x128 tile, BK=64, 4 waves, single-buffer 32KB, swizzled ----------
// Post-mortem r2: 256-tiles -> 1 block/CU -> lockstep barrier drains idle the whole CU
// (MfmaUtil 11%). The binding constraint is REAL blocks per CU (dead early-exit blocks hide
// nothing). Fix: 128^2 tile (32KB LDS -> 5 blocks/CU capacity), m97-style 2-barrier loop
// relying on inter-block overlap (m114), and K-split=2 in phase 2 so both phases have
// ~1024 real blocks (~4/CU). Swizzle retained from r2 (measured conflicts = 0):
// rows are 128B = 8 x 16B chunks; physical chunk = logical ^ (row&7); global source is
// pre-swizzled per lane (rule #21: linear LDS dest), ds_read applies the same XOR.
// PHASE 1: h = relu(x_sel @ w1[e]^T + b1[e]) -> hb (bf16).        KB = 1024, nk = 16
// PHASE 2: out[token] += wgt*(h @ w2[e]^T + sp==0 ? b2[e] : 0).   KB = 1024 (x2 splits)
template <int PHASE>
__global__ __launch_bounds__(256, 4) void moe_gemm(
    const u16* __restrict__ Abuf,   // PHASE1: xb [4096][1024]; PHASE2: hb [8192][2048]
    const u16* __restrict__ Bbuf,   // bf16 weights: [NE][NDIM][KDIM_T] (K contiguous)
    const float* __restrict__ bias, // [NE][NDIM] fp32
    const int* __restrict__ counts, const int* __restrict__ offsets,
    const int* __restrict__ slot_token, const float* __restrict__ slot_wgt,
    u16* __restrict__ hb, float* __restrict__ out)
{
    constexpr int KDIM_T = (PHASE == 1) ? DI : DH;   // full K (A/B row stride)
    constexpr int KB = 1024;                         // K handled per block (both phases)
    constexpr int NS = (PHASE == 1) ? 1 : 2;         // K-splits
    constexpr int NDIM = (PHASE == 1) ? DH : DOUT;
    constexpr int BM = 128, BN = 128, BK = 64;       // row = 128B = 8 x 16B chunks
    constexpr int GA = BM / 8, GB = BN / 8;          // 16 + 16 staging groups (1KB each)
    constexpr int GPW = (GA + GB) / 4;               // 8 async16 per wave
    constexpr int NT = NDIM / BN;                    // 16 / 8
    constexpr int MT = B_TOK / BM;                   // 32
    constexpr int TOTAL = NE * NS * NT * MT;         // 8192 both phases
    constexpr int PER_XCD = TOTAL / 8;               // 1024

    // XCD-chunked bijective swizzle; e-major -> split -> n-tile -> m-tile (mt-consecutive
    // blocks share a 256KB B panel in their XCD's L2; each XCD owns exactly 2 experts)
    const int id = blockIdx.x;
    const int wg = (id & 7) * PER_XCD + (id >> 3);
    const int e   = wg / (NS * NT * MT);
    int rem = wg % (NS * NT * MT);
    const int sp  = rem / (NT * MT);
    rem %= (NT * MT);
    const int nt  = rem / MT;
    const int mt  = rem % MT;

    const int cnt = counts[e];
    const int m0 = mt * BM;
    if (m0 >= cnt) return;                    // block-uniform early exit (before any barrier)
    const int n0 = nt * BN;
    const int sbase = offsets[e];
    const int koff = sp * KB;                 // element offset into K

    __shared__ u16 lds[(BM + BN) * BK];       // 32 KB single buffer

    const int tid = threadIdx.x;
    const int wv = tid >> 6, lane = tid & 63;
    const int quad = lane >> 4, mr = lane & 15;
    const int wr = wv >> 1, wc = wv & 1;      // 2x2 wave grid, 64x64 per wave

    // ---- staging pointers: per-lane global source, pre-swizzled (rule #21) ----
    // lane covers (r = lane>>3, s = lane&7) of an 8-row x 128B group; fetches chunk s^r
    const int sr_ = lane >> 3, sc_ = lane & 7;
    const int sw = (sc_ ^ sr_) * 8;                        // u16 offset within 128B row seg
    const u16* gptr[GPW];
#pragma unroll
    for (int j = 0; j < GPW; ++j) {
        const int G = wv * GPW + j;                        // wave-uniform group id
        if (G < GA) {                                      // A group: tile rows 8G..8G+7
            int row = G * 8 + sr_;
            if (PHASE == 1) {
                int rr = m0 + row; if (rr > cnt - 1) rr = cnt - 1;
                gptr[j] = Abuf + (size_t)slot_token[sbase + rr] * KDIM_T + koff + sw;
            } else {
                int s2 = sbase + m0 + row; if (s2 > NSLOT - 1) s2 = NSLOT - 1;
                gptr[j] = Abuf + (size_t)s2 * KDIM_T + koff + sw;
            }
        } else {                                           // B group
            int row = (G - GA) * 8 + sr_;
            gptr[j] = Bbuf + (size_t)e * NDIM * KDIM_T + (size_t)(n0 + row) * KDIM_T + koff + sw;
        }
    }

    f32x4 acc[4][4];
#pragma unroll
    for (int i = 0; i < 4; ++i)
#pragma unroll
        for (int j = 0; j < 4; ++j) acc[i][j] = (f32x4){0.f, 0.f, 0.f, 0.f};

    constexpr int nk = KB / BK;               // 16
    for (int kt = 0; kt < nk; ++kt) {
        // stage tile kt (8 x async16/wave; LDS dest linear, source pre-swizzled)
#pragma unroll
        for (int j = 0; j < GPW; ++j)
            async16(gptr[j] + kt * BK, &lds[(wv * GPW + j) * 512]);
        __syncthreads();                       // vmcnt(0) drain -> tile visible
        const u16* al = &lds[0];
        const u16* bl = al + BM * BK;
#pragma unroll
        for (int ks = 0; ks < 2; ++ks) {       // two 32-wide k-slices per BK=64
            const int cp = ((ks * 4 + quad) ^ (mr & 7)) * 8;   // swizzled chunk (u16 units)
            bfrag bf[4];
#pragma unroll
            for (int nf = 0; nf < 4; ++nf)
                bf[nf] = *(const bfrag*)(bl + (wc * 64 + nf * 16 + mr) * BK + cp);
#pragma unroll
            for (int mf = 0; mf < 4; ++mf) {
                bfrag af = *(const bfrag*)(al + (wr * 64 + mf * 16 + mr) * BK + cp);
#pragma unroll
                for (int nf = 0; nf < 4; ++nf)
                    acc[mf][nf] = __builtin_amdgcn_mfma_f32_16x16x32_bf16(af, bf[nf], acc[mf][nf], 0, 0, 0);
            }
        }
        __syncthreads();   // all reads done before next stage overwrites
    }

    // epilogue. C/D layout: n = lane&15 (=mr), m = quad*4 + reg  [m89-verified]
    const float* bias_e = bias + e * NDIM;
    if constexpr (PHASE == 1) {
#pragma unroll
        for (int mf = 0; mf < 4; ++mf) {
            int mbase = wr * 64 + mf * 16 + quad * 4;
#pragma unroll
            for (int nf = 0; nf < 4; ++nf) {
                int n = n0 + wc * 64 + nf * 16 + mr;
                float bv = bias_e[n];
#pragma unroll
                for (int r = 0; r < 4; ++r) {
                    int m = m0 + mbase + r;
                    if (m < cnt) {
                        float v = acc[mf][nf][r] + bv;
                        v = v > 0.f ? v : 0.f;
                        hb[(size_t)(sbase + m) * DH + n] = f2bf(v);
                    }
                }
            }
        }
    } else {
#pragma unroll
        for (int mf = 0; mf < 4; ++mf) {
            int mbase = wr * 64 + mf * 16 + quad * 4;
#pragma unroll
            for (int r = 0; r < 4; ++r) {
                int m = m0 + mbase + r;
                if (m < cnt) {
                    int slot = sbase + m;
                    int tok = slot_token[slot];
                    float wgt = slot_wgt[slot];
                    float* orow = out + (size_t)tok * DOUT + n0 + wc * 64;
#pragma unroll
                    for (int nf = 0; nf < 4; ++nf) {
                        int nl = nf * 16 + mr;
                        float v = acc[mf][nf][r];
                        if (sp == 0) v += bias_e[n0 + wc * 64 + nl];   // bias once per token
                        atomicAdd(orow + nl, wgt * v);
                    }
                }
            }
        }
    }
}

// ---------- launch ----------
extern "C" void kernel_launch(void* const* d_in, const int* in_sizes, int n_in,
                              void* d_out, int out_size, void* d_ws, size_t ws_size,
                              hipStream_t stream) {
    const float* x  = (const float*)d_in[0];   // [4096][1024]
    const float* gw = (const float*)d_in[1];   // [16][1024]
    const float* w1 = (const float*)d_in[2];   // [16][2048][1024]
    const float* b1 = (const float*)d_in[3];   // [16][2048]
    const float* w2 = (const float*)d_in[4];   // [16][1024][2048]
    const float* b2 = (const float*)d_in[5];   // [16][1024]
    float* out = (float*)d_out;                // [4096][1024] fp32

    // workspace layout (~104.1 MiB)
    char* ws = (char*)d_ws;
    u16* xb = (u16*)ws;                                   //  8,388,608 B
    u16* wb = (u16*)(ws + 8388608);                       // 67,108,864 B (w1 then reused for w2)
    u16* hb = (u16*)(ws + 8388608 + 67108864);            // 33,554,432 B
    char* rb = ws + 109051904;
    int*   counts     = (int*)(rb);
    int*   offsets    = (int*)(rb + 64);
    int*   token_e    = (int*)(rb + 192);
    float* token_w    = (float*)(rb + 192 + 32768);
    int*   slot_token = (int*)(rb + 192 + 65536);
    float* slot_wgt   = (float*)(rb + 192 + 98304);

    zero_init<<<4096, 256, 0, stream>>>(out, (B_TOK * DOUT) / 4);
    convert_bf16<<<16384, 256, 0, stream>>>(w1, wb, (NE * DH * DI) / 8);
    gate_topk<<<1024, 256, 0, stream>>>(x, gw, token_e, token_w, xb);  // fused x->bf16
    route<<<1, 1024, 0, stream>>>(token_e, token_w, counts, offsets, slot_token, slot_wgt);
    moe_gemm<1><<<NE * 1 * (DH / 128) * (B_TOK / 128), 256, 0, stream>>>(
        xb, wb, b1, counts, offsets, slot_token, slot_wgt, hb, out);
    convert_bf16<<<16384, 256, 0, stream>>>(w2, wb, (NE * DOUT * DH) / 8);
    moe_gemm<2><<<NE * 2 * (DOUT / 128) * (B_TOK / 128), 256, 0, stream>>>(
        hb, wb, b2, counts, offsets, slot_token, slot_wgt, hb, out);
}